// Round 1
// baseline (293.212 us; speedup 1.0000x reference)
//
#include <hip/hip_runtime.h>

#define NB 16
#define NC 256
#define NH 64
#define NW 64
#define PATCH 9
#define TROWS 4                      // pixel rows per block tile
#define YROWS (TROWS + 8)            // 12 y-rows incl. vertical halo
#define YCOLS (NW + 8)               // 72 cols incl. horizontal halo
#define BLOCK_THREADS (PATCH * 64)   // 576 = 9 waves; wave w handles di=w
#define CHSTRIDE (NH * NW)           // 4096 floats per channel plane

// out[b, di*9+dj, i, j] = (1/C) * sum_c x[b,c,i,j] * y[b,c,i+di-4, j+dj-4]
__global__ void __launch_bounds__(BLOCK_THREADS)
corr_kernel(const float* __restrict__ x, const float* __restrict__ y,
            float* __restrict__ out)
{
    // double-buffered y tile; halo zeroed once and never overwritten
    __shared__ __align__(16) float ytile[2][YROWS][YCOLS];

    const int tid  = threadIdx.x;
    const int di   = tid >> 6;           // 0..8, wave-uniform
    const int px   = tid & 63;
    const int prow = px >> 4;            // 0..3 pixel row within tile
    const int j0   = (px & 15) << 2;     // pixel col base, multiple of 4

    const int blk = blockIdx.x;          // 256 blocks
    const int b   = blk >> 4;
    const int r0  = (blk & 15) * TROWS;

    const int i        = r0 + prow;      // output pixel row
    const int yrow_idx = prow + di;      // 0..11, row within LDS tile

    // zero both LDS buffers (halo persists as zero across all channels)
    for (int k = tid; k < 2 * YROWS * YCOLS; k += BLOCK_THREADS)
        ((float*)ytile)[k] = 0.0f;

    // staging role: threads 0..191 stage 12 rows x 64 cols (float4 each)
    const int st_row = tid >> 4;                 // 0..35 (only <12 used)
    const int st_col = (tid & 15) << 2;          // 0..60
    const int g_row  = r0 - 4 + st_row;          // global y row (may be OOB)
    const bool do_stage = (st_row < YROWS) && (g_row >= 0) && (g_row < NH);
    const int g_row_c = do_stage ? g_row : 0;    // clamp for safe pointer math

    const float* xp = x + ((b * NC) * NH + i) * NW + j0;
    const float* yp = y + ((b * NC) * NH + g_row_c) * NW + st_col;

    float acc[PATCH][4];
    #pragma unroll
    for (int dj = 0; dj < PATCH; ++dj)
        #pragma unroll
        for (int t = 0; t < 4; ++t)
            acc[dj][t] = 0.0f;

    // prefetch channel 0 and stage it into buffer 0
    float4 xv = *(const float4*)xp;
    float4 y0 = make_float4(0.f, 0.f, 0.f, 0.f);
    if (do_stage) y0 = *(const float4*)yp;
    if (do_stage) *(float4*)&ytile[0][st_row][st_col + 4] = y0;

    for (int c = 0; c < NC; ++c) {
        __syncthreads();   // buf[c&1] staging visible; prior reads of buf[(c+1)&1] done

        // prefetch channel c+1 (global latency hides behind FMAs below)
        const int cn = (c + 1 < NC) ? c + 1 : c;
        float4 xn = *(const float4*)(xp + cn * CHSTRIDE);
        float4 yn = make_float4(0.f, 0.f, 0.f, 0.f);
        if (do_stage) yn = *(const float4*)(yp + cn * CHSTRIDE);

        // 12-float sliding window: cols j0-4 .. j0+7 (halo-adjusted, b128 aligned)
        const float* wrow = &ytile[c & 1][yrow_idx][j0];
        float wb[12];
        *(float4*)&wb[0] = *(const float4*)(wrow);
        *(float4*)&wb[4] = *(const float4*)(wrow + 4);
        *(float4*)&wb[8] = *(const float4*)(wrow + 8);

        const float xs[4] = {xv.x, xv.y, xv.z, xv.w};
        #pragma unroll
        for (int dj = 0; dj < PATCH; ++dj)
            #pragma unroll
            for (int t = 0; t < 4; ++t)
                acc[dj][t] = fmaf(xs[t], wb[t + dj], acc[dj][t]);

        // stage channel c+1 into the other buffer (safe: its readers are
        // either past (iter c-1, pre-barrier) or future (post next barrier))
        if (do_stage) *(float4*)&ytile[(c + 1) & 1][st_row][st_col + 4] = yn;

        xv = xn;
    }

    // epilogue: scale by 1/C, coalesced float4 stores; every output covered once
    const float scale = 1.0f / (float)NC;
    float* op = out + (((b * (PATCH * PATCH)) + di * PATCH) * NH + i) * NW + j0;
    #pragma unroll
    for (int dj = 0; dj < PATCH; ++dj) {
        float4 o = make_float4(acc[dj][0] * scale, acc[dj][1] * scale,
                               acc[dj][2] * scale, acc[dj][3] * scale);
        *(float4*)(op + dj * CHSTRIDE) = o;
    }
}

extern "C" void kernel_launch(void* const* d_in, const int* in_sizes, int n_in,
                              void* d_out, int out_size, void* d_ws, size_t ws_size,
                              hipStream_t stream)
{
    const float* x = (const float*)d_in[0];
    const float* y = (const float*)d_in[1];
    float* out = (float*)d_out;

    dim3 grid(NB * (NH / TROWS));   // 16 batches * 16 row-tiles = 256 blocks
    dim3 block(BLOCK_THREADS);      // 576 threads = 9 waves
    hipLaunchKernelGGL(corr_kernel, grid, block, 0, stream, x, y, out);
}

// Round 3
// 213.589 us; speedup vs baseline: 1.3728x; 1.3728x over previous
//
#include <hip/hip_runtime.h>

#define NB 16
#define NC 256
#define NH 64
#define NW 64
#define PATCH 9
#define TROWS 4
#define CHST (NH * NW)               // channel plane stride (floats)
#define BLOCK_THREADS 192            // 3 waves; wave w handles di = 3*g + w

// DPP 16-lane-row shifts. CDNA semantics:
//   row_shr:1 (0x111): lane l  <-  lane l-1   (first lane of row -> 0)
//   row_shl:1 (0x101): lane l  <-  lane l+1   (last  lane of row -> 0)
// Our 16-lane col-groups coincide exactly with DPP rows, so the shifted-in
// zeros implement the horizontal zero-padding of y for free.
__device__ __forceinline__ float from_prev_lane(float v) {  // lane l <- lane l-1
    return __int_as_float(__builtin_amdgcn_update_dpp(
        0, __float_as_int(v), 0x111, 0xF, 0xF, true));      // row_shr:1
}
__device__ __forceinline__ float from_next_lane(float v) {  // lane l <- lane l+1
    return __int_as_float(__builtin_amdgcn_update_dpp(
        0, __float_as_int(v), 0x101, 0xF, 0xF, true));      // row_shl:1
}

// out[b, di*9+dj, i, j] = (1/C) * sum_c x[b,c,i,j] * y[b,c,i+di-4, j+dj-4]
__global__ void __launch_bounds__(BLOCK_THREADS)
corr_kernel(const float* __restrict__ x, const float* __restrict__ y,
            float* __restrict__ out, const float* __restrict__ zpad)
{
    const int tid  = threadIdx.x;
    const int w    = tid >> 6;           // wave 0..2
    const int ln   = tid & 63;
    const int prow = ln >> 4;            // pixel row within tile (DPP-row index)
    const int j0   = (ln & 15) << 2;     // col base, lane order == col order

    // blk = g*256 + b*16 + t
    const int blk = blockIdx.x;
    const int g   = blk >> 8;            // di triple 0..2
    const int rem = blk & 255;
    const int b   = rem >> 4;
    const int t   = rem & 15;
    const int r0  = t * TROWS;

    const int di = g * 3 + w;            // 0..8, wave-uniform
    const int i  = r0 + prow;            // output pixel row
    const int yr = i + di - 4;           // y row this thread needs
    const bool rv = (yr >= 0) && (yr < NH);

    // x: always valid. y: invalid rows read a zeroed ws region with stride 0.
    const float* xp = x + ((size_t)(b * NC) * NH + i) * NW + j0;
    const float* yp = rv ? (y + ((size_t)(b * NC) * NH + yr) * NW + j0)
                         : (zpad + j0);
    const size_t ystep = rv ? (size_t)CHST : 0;

    float acc[PATCH][4];
    #pragma unroll
    for (int dj = 0; dj < PATCH; ++dj)
        #pragma unroll
        for (int tt = 0; tt < 4; ++tt) acc[dj][tt] = 0.0f;

    // depth-2 register prefetch pipeline (no LDS, no barriers)
    float4 xa = *(const float4*)(xp);
    float4 ya = *(const float4*)(yp);
    float4 xb = *(const float4*)(xp + CHST);
    float4 yb = *(const float4*)(yp + ystep);

    #pragma unroll 2
    for (int c = 0; c < NC; ++c) {
        const int cn = (c + 2 < NC) ? c + 2 : c;     // harmless tail reload
        float4 xn = *(const float4*)(xp + (size_t)cn * CHST);
        float4 yn = *(const float4*)(yp + (size_t)cn * ystep);

        // 12-float window [j0-4, j0+8): neighbors via DPP, edges auto-zero
        float wnd[12];
        wnd[0]  = from_prev_lane(ya.x);  wnd[1]  = from_prev_lane(ya.y);
        wnd[2]  = from_prev_lane(ya.z);  wnd[3]  = from_prev_lane(ya.w);
        wnd[4]  = ya.x;                  wnd[5]  = ya.y;
        wnd[6]  = ya.z;                  wnd[7]  = ya.w;
        wnd[8]  = from_next_lane(ya.x);  wnd[9]  = from_next_lane(ya.y);
        wnd[10] = from_next_lane(ya.z);  wnd[11] = from_next_lane(ya.w);

        const float xs[4] = {xa.x, xa.y, xa.z, xa.w};
        #pragma unroll
        for (int dj = 0; dj < PATCH; ++dj)
            #pragma unroll
            for (int tt = 0; tt < 4; ++tt)
                acc[dj][tt] = fmaf(xs[tt], wnd[tt + dj], acc[dj][tt]);

        xa = xb; xb = xn; ya = yb; yb = yn;
    }

    // epilogue: scale, coalesced float4 stores (each output written once)
    const float scale = 1.0f / (float)NC;
    float* op = out + (((size_t)b * (PATCH * PATCH) + di * PATCH) * NH + i) * NW + j0;
    #pragma unroll
    for (int dj = 0; dj < PATCH; ++dj) {
        float4 o = make_float4(acc[dj][0] * scale, acc[dj][1] * scale,
                               acc[dj][2] * scale, acc[dj][3] * scale);
        *(float4*)(op + (size_t)dj * CHST) = o;
    }
}

extern "C" void kernel_launch(void* const* d_in, const int* in_sizes, int n_in,
                              void* d_out, int out_size, void* d_ws, size_t ws_size,
                              hipStream_t stream)
{
    const float* x = (const float*)d_in[0];
    const float* y = (const float*)d_in[1];
    float* out = (float*)d_out;

    // zero page for out-of-range y rows (ws is re-poisoned every launch)
    hipMemsetAsync(d_ws, 0, 1024, stream);

    dim3 grid(3 * NB * (NH / TROWS));   // 3 di-triples * 16 b * 16 row-tiles = 768
    dim3 block(BLOCK_THREADS);          // 192 threads = 3 waves (no barriers used)
    hipLaunchKernelGGL(corr_kernel, grid, block, 0, stream, x, y, out,
                       (const float*)d_ws);
}